// Round 2
// baseline (7527.506 us; speedup 1.0000x reference)
//
#include <hip/hip_runtime.h>

// Problem dims (fixed)
#define BATCH 32
#define SEQ   512
#define DMOD  1024
#define DFFN  4096
#define NHEAD 16
#define DHEAD 64
#define NLAY  4
#define NTOK  (BATCH * SEQ)   // 16384

typedef __attribute__((ext_vector_type(8))) short short8;
typedef __attribute__((ext_vector_type(4))) float f32x4;
typedef unsigned int uint32;

__device__ __forceinline__ unsigned short f2bf(float f) {
  uint32 u = __builtin_bit_cast(uint32, f);
  u += 0x7fffu + ((u >> 16) & 1u);             // RNE
  return (unsigned short)(u >> 16);
}
__device__ __forceinline__ float bflo(uint32 u) { return __builtin_bit_cast(float, u << 16); }
__device__ __forceinline__ float bfhi(uint32 u) { return __builtin_bit_cast(float, u & 0xffff0000u); }
__device__ __forceinline__ uint32 packbf(float a, float b) {
  return (uint32)f2bf(a) | ((uint32)f2bf(b) << 16);
}
__device__ __forceinline__ float gelu_f(float x) {
  float u = 0.7978845608028654f * (x + 0.044715f * x * x * x);
  u = fminf(fmaxf(u, -15.f), 15.f);
  float e = __expf(2.f * u);
  return 0.5f * x * (1.f + (e - 1.f) / (e + 1.f));
}

#define GLOAD16(g, l) __builtin_amdgcn_global_load_lds( \
    (const __attribute__((address_space(1))) void*)(g), \
    (__attribute__((address_space(3))) void*)(l), 16, 0, 0)

// ---------------- positional encoding table: pe[l][d], 512x1024 ----------------
__global__ __launch_bounds__(256) void pe_kernel(float* __restrict__ pe) {
  const int idx = blockIdx.x * 256 + threadIdx.x;   // 0 .. 512*512-1 (pairs)
  const int l = idx >> 9;
  const int i = idx & 511;
  const float dv = __expf((float)(2 * i) * (-9.210340371976184f / (float)DMOD));
  const float a = (float)l * dv;
  pe[(size_t)l * DMOD + 2 * i]     = sinf(a);
  pe[(size_t)l * DMOD + 2 * i + 1] = cosf(a);
}

// ---------------- x + pe + speaker -> (optional f32) + bf16 ----------------
__global__ __launch_bounds__(256) void prep_kernel(
    const float* __restrict__ x, const float* __restrict__ pe, const float* __restrict__ spk,
    float* __restrict__ of32, unsigned short* __restrict__ o16)
{
  const size_t id4 = (size_t)blockIdx.x * 256 + threadIdx.x;  // over B*L*D/4
  const size_t e = id4 * 4;
  const int b  = (int)(e >> 19);                 // / (512*1024)
  const int ld = (int)(e & ((1u << 19) - 1));    // l*1024 + d
  const int d  = (int)(e & 1023);
  float4 xv = ((const float4*)x)[id4];
  float4 pv = ((const float4*)pe)[ld >> 2];
  float4 sv = ((const float4*)spk)[(size_t)b * 256 + (d >> 2)];
  float4 o;
  o.x = xv.x + pv.x + sv.x;
  o.y = xv.y + pv.y + sv.y;
  o.z = xv.z + pv.z + sv.z;
  o.w = xv.w + pv.w + sv.w;
  if (of32) ((float4*)of32)[id4] = o;
  ushort4 h;
  h.x = f2bf(o.x); h.y = f2bf(o.y); h.z = f2bf(o.z); h.w = f2bf(o.w);
  ((ushort4*)o16)[id4] = h;
}

// ---------------- weight transpose+cast: W[K][N] f32 -> Wt[N][K] bf16 ----------------
__global__ __launch_bounds__(256) void wtrans_kernel(
    const float* __restrict__ W, unsigned short* __restrict__ Wt, int K, int N)
{
  __shared__ float tile[64][65];
  const int n0 = blockIdx.x * 64, k0 = blockIdx.y * 64;
  const int tx = threadIdx.x & 63, ty = threadIdx.x >> 6;
  #pragma unroll
  for (int i = 0; i < 16; i++) {
    int r = ty + 4 * i;
    tile[r][tx] = W[(size_t)(k0 + r) * N + n0 + tx];
  }
  __syncthreads();
  #pragma unroll
  for (int i = 0; i < 16; i++) {
    int rn = ty + 4 * i;
    Wt[(size_t)(n0 + rn) * K + k0 + tx] = f2bf(tile[tx][rn]);
  }
}

// ---------------- LayerNorm: one block per row (1024 cols) ----------------
template<int WRITE_F32>
__global__ __launch_bounds__(256) void ln_kernel(
    const float* __restrict__ x, const float* __restrict__ g, const float* __restrict__ bta,
    float* __restrict__ of32, unsigned short* __restrict__ o16)
{
  const int row = blockIdx.x;
  const int t = threadIdx.x;
  const float4 v = ((const float4*)(x + (size_t)row * DMOD))[t];
  float s  = v.x + v.y + v.z + v.w;
  float s2 = v.x*v.x + v.y*v.y + v.z*v.z + v.w*v.w;
  #pragma unroll
  for (int off = 32; off > 0; off >>= 1) {
    s  += __shfl_down(s, off);
    s2 += __shfl_down(s2, off);
  }
  __shared__ float red[8];
  if ((t & 63) == 0) { red[(t >> 6) * 2] = s; red[(t >> 6) * 2 + 1] = s2; }
  __syncthreads();
  const float sum  = red[0] + red[2] + red[4] + red[6];
  const float sum2 = red[1] + red[3] + red[5] + red[7];
  const float mean = sum * (1.f / (float)DMOD);
  const float var  = sum2 * (1.f / (float)DMOD) - mean * mean;
  const float rstd = rsqrtf(var + 1e-6f);
  const float4 gg = ((const float4*)g)[t];
  const float4 bb = ((const float4*)bta)[t];
  float4 o;
  o.x = (v.x - mean) * rstd * gg.x + bb.x;
  o.y = (v.y - mean) * rstd * gg.y + bb.y;
  o.z = (v.z - mean) * rstd * gg.z + bb.z;
  o.w = (v.w - mean) * rstd * gg.w + bb.w;
  if (WRITE_F32) ((float4*)of32)[(size_t)row * 256 + t] = o;
  ushort4 h;
  h.x = f2bf(o.x); h.y = f2bf(o.y); h.z = f2bf(o.z); h.w = f2bf(o.w);
  ((ushort4*)o16)[(size_t)row * 256 + t] = h;
}

// ---------------- GEMM: C = A(MxK,bf16) * Bt(NxK,bf16)^T + bias, m97-style ----------------
// EPI: 0 = bias -> bf16 ; 1 = bias+gelu -> bf16 ;
//      2 = bias + res(f32, distinct) -> f32 ; 3 = bias + in-place add -> f32
template<int EPI>
__global__ __launch_bounds__(256) void gemm_bt(
    const unsigned short* __restrict__ A, const unsigned short* __restrict__ Bt,
    const float* __restrict__ bias, const float* __restrict__ res,
    void* outp, int N, int K)
{
  __shared__ unsigned short As[128 * 32];
  __shared__ unsigned short Bs[128 * 32];
  const int t = threadIdx.x;
  const int lane = t & 63, w = t >> 6;
  const int wr = w >> 1, wc = w & 1;
  const size_t tm = (size_t)blockIdx.y * 128;
  const size_t tn = (size_t)blockIdx.x * 128;

  // staging: 512 16B-chunks per tile; wave w, lane l handles chunk w*64+l and +256
  const int ia1 = w * 64 + lane;
  const int r1 = ia1 >> 2, c1 = (ia1 & 3) * 8;
  const unsigned short* a1 = A  + (tm + r1) * (size_t)K + c1;
  const unsigned short* a2 = A  + (tm + r1 + 64) * (size_t)K + c1;
  const unsigned short* b1 = Bt + (tn + r1) * (size_t)K + c1;
  const unsigned short* b2 = Bt + (tn + r1 + 64) * (size_t)K + c1;
  unsigned short* sA1 = As + w * 512;
  unsigned short* sA2 = As + 2048 + w * 512;
  unsigned short* sB1 = Bs + w * 512;
  unsigned short* sB2 = Bs + 2048 + w * 512;

  f32x4 acc[4][4];
  #pragma unroll
  for (int i = 0; i < 4; i++)
    #pragma unroll
    for (int j = 0; j < 4; j++)
      acc[i][j] = (f32x4){0.f, 0.f, 0.f, 0.f};

  const int ko = (lane >> 4) * 8;   // k-offset of this lane's 8 elements
  const int rm = lane & 15;

  for (int k0 = 0; k0 < K; k0 += 32) {
    GLOAD16(a1 + k0, sA1);
    GLOAD16(a2 + k0, sA2);
    GLOAD16(b1 + k0, sB1);
    GLOAD16(b2 + k0, sB2);
    __syncthreads();
    short8 af[4], bfv[4];
    #pragma unroll
    for (int fm = 0; fm < 4; fm++)
      af[fm] = *(const short8*)(As + (wr * 64 + fm * 16 + rm) * 32 + ko);
    #pragma unroll
    for (int fn = 0; fn < 4; fn++)
      bfv[fn] = *(const short8*)(Bs + (wc * 64 + fn * 16 + rm) * 32 + ko);
    #pragma unroll
    for (int fm = 0; fm < 4; fm++)
      #pragma unroll
      for (int fn = 0; fn < 4; fn++)
        acc[fm][fn] = __builtin_amdgcn_mfma_f32_16x16x32_bf16(af[fm], bfv[fn], acc[fm][fn], 0, 0, 0);
    __syncthreads();
  }

  #pragma unroll
  for (int fn = 0; fn < 4; fn++) {
    const size_t gcol = tn + wc * 64 + fn * 16 + rm;
    const float bc = bias[gcol];
    #pragma unroll
    for (int fm = 0; fm < 4; fm++) {
      #pragma unroll
      for (int r = 0; r < 4; r++) {
        const size_t grow = tm + wr * 64 + fm * 16 + (lane >> 4) * 4 + r;
        const size_t off = grow * (size_t)N + gcol;
        float v = acc[fm][fn][r] + bc;
        if (EPI == 0) {
          ((unsigned short*)outp)[off] = f2bf(v);
        } else if (EPI == 1) {
          ((unsigned short*)outp)[off] = f2bf(gelu_f(v));
        } else if (EPI == 2) {
          ((float*)outp)[off] = v + res[off];
        } else {
          float* op = (float*)outp;          // in-place: read old, add, write
          op[off] = v + op[off];
        }
      }
    }
  }
}

// ---------------- attention: one block per (b,h); K/V L2-resident (no LDS) ----------------
// ctx may alias qb: each thread reads its own q-row into registers before writing
// the same ctx row; no cross-thread/block overlap.
__global__ __launch_bounds__(256) void attn_kernel(
    const unsigned short* __restrict__ qb, const unsigned short* __restrict__ kb,
    const unsigned short* __restrict__ vb, unsigned short* ctx)
{
  const int t = threadIdx.x;
  const int h = blockIdx.x, b = blockIdx.y;
  const size_t base = ((size_t)b * SEQ) * DMOD + (size_t)h * DHEAD;

  for (int qi = 0; qi < 2; qi++) {
    const int ql = qi * 256 + t;
    const unsigned short* qrow = qb + base + (size_t)ql * DMOD;
    float qv[64];
    #pragma unroll
    for (int c = 0; c < 8; c++) {
      uint4 u = *(const uint4*)(qrow + c * 8);
      qv[c*8+0]=bflo(u.x); qv[c*8+1]=bfhi(u.x);
      qv[c*8+2]=bflo(u.y); qv[c*8+3]=bfhi(u.y);
      qv[c*8+4]=bflo(u.z); qv[c*8+5]=bfhi(u.z);
      qv[c*8+6]=bflo(u.w); qv[c*8+7]=bfhi(u.w);
    }
    float m = -INFINITY, ssum = 0.f;
    float acc[64];
    #pragma unroll
    for (int d = 0; d < 64; d++) acc[d] = 0.f;

    for (int j = 0; j < SEQ; j++) {
      const unsigned short* krow = kb + base + (size_t)j * DMOD;
      float s = 0.f;
      #pragma unroll
      for (int c = 0; c < 8; c++) {
        uint4 u = *(const uint4*)(krow + c * 8);
        s += qv[c*8+0]*bflo(u.x) + qv[c*8+1]*bfhi(u.x)
           + qv[c*8+2]*bflo(u.y) + qv[c*8+3]*bfhi(u.y)
           + qv[c*8+4]*bflo(u.z) + qv[c*8+5]*bfhi(u.z)
           + qv[c*8+6]*bflo(u.w) + qv[c*8+7]*bfhi(u.w);
      }
      s *= 0.125f;   // 1/sqrt(64)
      const float mn = fmaxf(m, s);
      const float corr = __expf(m - mn);
      const float p = __expf(s - mn);
      ssum = ssum * corr + p;
      const unsigned short* vrow = vb + base + (size_t)j * DMOD;
      #pragma unroll
      for (int c = 0; c < 8; c++) {
        uint4 u = *(const uint4*)(vrow + c * 8);
        acc[c*8+0] = acc[c*8+0]*corr + p*bflo(u.x);
        acc[c*8+1] = acc[c*8+1]*corr + p*bfhi(u.x);
        acc[c*8+2] = acc[c*8+2]*corr + p*bflo(u.y);
        acc[c*8+3] = acc[c*8+3]*corr + p*bfhi(u.y);
        acc[c*8+4] = acc[c*8+4]*corr + p*bflo(u.z);
        acc[c*8+5] = acc[c*8+5]*corr + p*bfhi(u.z);
        acc[c*8+6] = acc[c*8+6]*corr + p*bflo(u.w);
        acc[c*8+7] = acc[c*8+7]*corr + p*bfhi(u.w);
      }
      m = mn;
    }
    const float inv = 1.f / ssum;
    unsigned short* crow = ctx + base + (size_t)ql * DMOD;
    #pragma unroll
    for (int c = 0; c < 8; c++) {
      uint4 u;
      u.x = packbf(acc[c*8+0]*inv, acc[c*8+1]*inv);
      u.y = packbf(acc[c*8+2]*inv, acc[c*8+3]*inv);
      u.z = packbf(acc[c*8+4]*inv, acc[c*8+5]*inv);
      u.w = packbf(acc[c*8+6]*inv, acc[c*8+7]*inv);
      *(uint4*)(crow + c * 8) = u;
    }
  }
}

extern "C" void kernel_launch(void* const* d_in, const int* in_sizes, int n_in,
                              void* d_out, int out_size, void* d_ws, size_t ws_size,
                              hipStream_t stream) {
  const float* x_a   = (const float*)d_in[0];
  const float* x_b   = (const float*)d_in[1];
  const float* spk   = (const float*)d_in[2];
  const float* Wq    = (const float*)d_in[3];
  const float* bq    = (const float*)d_in[4];
  const float* Wk    = (const float*)d_in[5];
  const float* bk    = (const float*)d_in[6];
  const float* Wv    = (const float*)d_in[7];
  const float* bv    = (const float*)d_in[8];
  const float* Wo    = (const float*)d_in[9];
  const float* bo    = (const float*)d_in[10];
  const float* ln_g  = (const float*)d_in[11];
  const float* ln_b  = (const float*)d_in[12];
  const float* fln_g = (const float*)d_in[13];
  const float* fln_b = (const float*)d_in[14];
  const float* W1    = (const float*)d_in[15];
  const float* b1    = (const float*)d_in[16];
  const float* W2    = (const float*)d_in[17];
  const float* b2    = (const float*)d_in[18];
  float* out = (float*)d_out;           // also serves as the f32 x_b master (X)

  // ---- workspace layout: ~250 MB total ----
  char* ws = (char*)d_ws;
  size_t o = 0;
  auto give = [&](size_t bytes) { char* p = ws + o; o += (bytes + 255) & ~(size_t)255; return p; };
  const size_t ACT2 = (size_t)NTOK * DMOD * 2;   // 32 MB bf16 activation

  unsigned short* qb16  = (unsigned short*)give(ACT2);       // also ctx; also inter lo
  unsigned short* kb16  = (unsigned short*)give(ACT2);       // also inter hi
  unsigned short* vb16  = (unsigned short*)give(ACT2);
  unsigned short* xa16  = (unsigned short*)give(ACT2);
  unsigned short* xbn16 = (unsigned short*)give(ACT2);
  float*          outf  = (float*)give((size_t)NTOK * DMOD * 4);   // 64 MB (residual stream)
  unsigned short* Wqt   = (unsigned short*)give((size_t)DMOD * DMOD * 2);  // 2 MB each
  unsigned short* Wkt   = (unsigned short*)give((size_t)DMOD * DMOD * 2);
  unsigned short* Wvt   = (unsigned short*)give((size_t)DMOD * DMOD * 2);
  unsigned short* Wot   = (unsigned short*)give((size_t)DMOD * DMOD * 2);
  unsigned short* W1t   = (unsigned short*)give((size_t)DMOD * DFFN * 2);  // 8 MB
  unsigned short* W2t   = (unsigned short*)give((size_t)DMOD * DFFN * 2);  // 8 MB
  float*          peb   = (float*)give((size_t)SEQ * DMOD * 4);            // 2 MB
  unsigned short* ctx16 = qb16;     // safe alias (see attn_kernel)
  unsigned short* inter = qb16;     // 64 MB span over qb16+kb16 (dead during FFN)
  (void)ws_size; (void)in_sizes; (void)n_in; (void)out_size;

  const dim3 blk(256);

  // one-time prep
  pe_kernel<<<dim3((SEQ * (DMOD / 2)) / 256), blk, 0, stream>>>(peb);
  const int nprep = (NTOK * DMOD / 4) / 256;  // 16384 blocks
  prep_kernel<<<dim3(nprep), blk, 0, stream>>>(x_a, peb, spk, nullptr, xa16);
  prep_kernel<<<dim3(nprep), blk, 0, stream>>>(x_b, peb, spk, out, xbn16);

  const dim3 g1024(DMOD / 128, NTOK / 128);   // (8,128)
  const int  MCH = NTOK / 2;                  // FFN token-chunk (8192 rows)

  for (int i = 0; i < NLAY; i++) {
    const size_t wo = (size_t)i * DMOD * DMOD;
    const size_t wf = (size_t)i * DMOD * DFFN;
    // per-layer weight transpose+cast (f32 [K][N] -> bf16 [N][K])
    wtrans_kernel<<<dim3(16, 16), blk, 0, stream>>>(Wq + wo, Wqt, DMOD, DMOD);
    wtrans_kernel<<<dim3(16, 16), blk, 0, stream>>>(Wk + wo, Wkt, DMOD, DMOD);
    wtrans_kernel<<<dim3(16, 16), blk, 0, stream>>>(Wv + wo, Wvt, DMOD, DMOD);
    wtrans_kernel<<<dim3(16, 16), blk, 0, stream>>>(Wo + wo, Wot, DMOD, DMOD);
    wtrans_kernel<<<dim3(64, 16), blk, 0, stream>>>(W1 + wf, W1t, DMOD, DFFN);
    wtrans_kernel<<<dim3(16, 64), blk, 0, stream>>>(W2 + wf, W2t, DFFN, DMOD);

    if (i != 0) {
      // xb_n = LN(X): f32 into outf (residual source), bf16 into xbn16
      ln_kernel<1><<<dim3(NTOK), blk, 0, stream>>>(out, ln_g + (size_t)i * DMOD, ln_b + (size_t)i * DMOD, outf, xbn16);
    }
    gemm_bt<0><<<g1024, blk, 0, stream>>>(xbn16, Wqt, bq + (size_t)i * DMOD, nullptr, qb16, DMOD, DMOD);
    gemm_bt<0><<<g1024, blk, 0, stream>>>(xa16,  Wkt, bk + (size_t)i * DMOD, nullptr, kb16, DMOD, DMOD);
    gemm_bt<0><<<g1024, blk, 0, stream>>>(xa16,  Wvt, bv + (size_t)i * DMOD, nullptr, vb16, DMOD, DMOD);
    attn_kernel<<<dim3(NHEAD, BATCH), blk, 0, stream>>>(qb16, kb16, vb16, ctx16);
    if (i == 0) {
      // residual = raw x_b(+pe+spk) f32 held in `out`; write outf
      gemm_bt<2><<<g1024, blk, 0, stream>>>(ctx16, Wot, bo + (size_t)i * DMOD, out, outf, DMOD, DMOD);
    } else {
      // residual = xb_n already sitting in outf; in-place add
      gemm_bt<3><<<g1024, blk, 0, stream>>>(ctx16, Wot, bo + (size_t)i * DMOD, nullptr, outf, DMOD, DMOD);
    }
    // FFN pre-LN
    ln_kernel<0><<<dim3(NTOK), blk, 0, stream>>>(outf, fln_g + (size_t)i * DMOD, fln_b + (size_t)i * DMOD, nullptr, xbn16);
    // FFN in two token-chunks so inter (64 MB) fits in qb16+kb16
    for (int c = 0; c < 2; c++) {
      const size_t moff = (size_t)c * MCH;
      gemm_bt<1><<<dim3(DFFN / 128, MCH / 128), blk, 0, stream>>>(
          xbn16 + moff * DMOD, W1t, b1 + (size_t)i * DFFN, nullptr, inter, DFFN, DMOD);
      gemm_bt<2><<<dim3(DMOD / 128, MCH / 128), blk, 0, stream>>>(
          inter, W2t, b2 + (size_t)i * DMOD, outf + moff * DMOD, out + moff * DMOD, DMOD, DFFN);
    }
  }
}

// Round 3
// 4052.425 us; speedup vs baseline: 1.8575x; 1.8575x over previous
//
#include <hip/hip_runtime.h>

// Problem dims (fixed)
#define BATCH 32
#define SEQ   512
#define DMOD  1024
#define DFFN  4096
#define NHEAD 16
#define DHEAD 64
#define NLAY  4
#define NTOK  (BATCH * SEQ)   // 16384

typedef __attribute__((ext_vector_type(8))) short short8;
typedef __attribute__((ext_vector_type(4))) float f32x4;
typedef unsigned int uint32;

__device__ __forceinline__ unsigned short f2bf(float f) {
  uint32 u = __builtin_bit_cast(uint32, f);
  u += 0x7fffu + ((u >> 16) & 1u);             // RNE
  return (unsigned short)(u >> 16);
}
__device__ __forceinline__ float gelu_f(float x) {
  float u = 0.7978845608028654f * (x + 0.044715f * x * x * x);
  u = fminf(fmaxf(u, -15.f), 15.f);
  float e = __expf(2.f * u);
  return 0.5f * x * (1.f + (e - 1.f) / (e + 1.f));
}

#define GLOAD16(g, l) __builtin_amdgcn_global_lo##ad_lds( \
    (const __attribute__((address_space(1))) void*)(g), \
    (__attribute__((address_space(3))) void*)(l), 16, 0, 0)
// (concatenation guard against accidental macro recursion; expands to the builtin)
#undef GLOAD16
#define GLOAD16(g, l) __builtin_amdgcn_global_load_lds( \
    (const __attribute__((address_space(1))) void*)(g), \
    (__attribute__((address_space(3))) void*)(l), 16, 0, 0)

#define MFMA16(a, b, c) __builtin_amdgcn_mfma_f32_16x16x32_bf16((a), (b), (c), 0, 0, 0)

// ---------------- positional encoding table: pe[l][d], 512x1024 ----------------
__global__ __launch_bounds__(256) void pe_kernel(float* __restrict__ pe) {
  const int idx = blockIdx.x * 256 + threadIdx.x;   // 0 .. 512*512-1 (pairs)
  const int l = idx >> 9;
  const int i = idx & 511;
  const float dv = __expf((float)(2 * i) * (-9.210340371976184f / (float)DMOD));
  const float a = (float)l * dv;
  pe[(size_t)l * DMOD + 2 * i]     = sinf(a);
  pe[(size_t)l * DMOD + 2 * i + 1] = cosf(a);
}

// ---------------- x + pe + speaker -> (optional f32) + bf16 ----------------
__global__ __launch_bounds__(256) void prep_kernel(
    const float* __restrict__ x, const float* __restrict__ pe, const float* __restrict__ spk,
    float* __restrict__ of32, unsigned short* __restrict__ o16)
{
  const size_t id4 = (size_t)blockIdx.x * 256 + threadIdx.x;  // over B*L*D/4
  const size_t e = id4 * 4;
  const int b  = (int)(e >> 19);                 // / (512*1024)
  const int ld = (int)(e & ((1u << 19) - 1));    // l*1024 + d
  const int d  = (int)(e & 1023);
  float4 xv = ((const float4*)x)[id4];
  float4 pv = ((const float4*)pe)[ld >> 2];
  float4 sv = ((const float4*)spk)[(size_t)b * 256 + (d >> 2)];
  float4 o;
  o.x = xv.x + pv.x + sv.x;
  o.y = xv.y + pv.y + sv.y;
  o.z = xv.z + pv.z + sv.z;
  o.w = xv.w + pv.w + sv.w;
  if (of32) ((float4*)of32)[id4] = o;
  ushort4 h;
  h.x = f2bf(o.x); h.y = f2bf(o.y); h.z = f2bf(o.z); h.w = f2bf(o.w);
  ((ushort4*)o16)[id4] = h;
}

// ---------------- weight transpose+cast: W[K][N] f32 -> Wt[N][K] bf16 ----------------
__global__ __launch_bounds__(256) void wtrans_kernel(
    const float* __restrict__ W, unsigned short* __restrict__ Wt, int K, int N)
{
  __shared__ float tile[64][65];
  const int n0 = blockIdx.x * 64, k0 = blockIdx.y * 64;
  const int tx = threadIdx.x & 63, ty = threadIdx.x >> 6;
  #pragma unroll
  for (int i = 0; i < 16; i++) {
    int r = ty + 4 * i;
    tile[r][tx] = W[(size_t)(k0 + r) * N + n0 + tx];
  }
  __syncthreads();
  #pragma unroll
  for (int i = 0; i < 16; i++) {
    int rn = ty + 4 * i;
    Wt[(size_t)(n0 + rn) * K + k0 + tx] = f2bf(tile[tx][rn]);
  }
}

// ---------------- LayerNorm: one block per row (1024 cols) ----------------
template<int WRITE_F32>
__global__ __launch_bounds__(256) void ln_kernel(
    const float* __restrict__ x, const float* __restrict__ g, const float* __restrict__ bta,
    float* __restrict__ of32, unsigned short* __restrict__ o16)
{
  const int row = blockIdx.x;
  const int t = threadIdx.x;
  const float4 v = ((const float4*)(x + (size_t)row * DMOD))[t];
  float s  = v.x + v.y + v.z + v.w;
  float s2 = v.x*v.x + v.y*v.y + v.z*v.z + v.w*v.w;
  #pragma unroll
  for (int off = 32; off > 0; off >>= 1) {
    s  += __shfl_down(s, off);
    s2 += __shfl_down(s2, off);
  }
  __shared__ float red[8];
  if ((t & 63) == 0) { red[(t >> 6) * 2] = s; red[(t >> 6) * 2 + 1] = s2; }
  __syncthreads();
  const float sum  = red[0] + red[2] + red[4] + red[6];
  const float sum2 = red[1] + red[3] + red[5] + red[7];
  const float mean = sum * (1.f / (float)DMOD);
  const float var  = sum2 * (1.f / (float)DMOD) - mean * mean;
  const float rstd = rsqrtf(var + 1e-6f);
  const float4 gg = ((const float4*)g)[t];
  const float4 bb = ((const float4*)bta)[t];
  float4 o;
  o.x = (v.x - mean) * rstd * gg.x + bb.x;
  o.y = (v.y - mean) * rstd * gg.y + bb.y;
  o.z = (v.z - mean) * rstd * gg.z + bb.z;
  o.w = (v.w - mean) * rstd * gg.w + bb.w;
  if (WRITE_F32) ((float4*)of32)[(size_t)row * 256 + t] = o;
  ushort4 h;
  h.x = f2bf(o.x); h.y = f2bf(o.y); h.z = f2bf(o.z); h.w = f2bf(o.w);
  ((ushort4*)o16)[(size_t)row * 256 + t] = h;
}

// ---------------- GEMM: C = A(MxK,bf16) * Bt(NxK,bf16)^T + bias, m97-style ----------------
// EPI: 0 = bias -> bf16 ; 1 = bias+gelu -> bf16 ;
//      2 = bias + res(f32, distinct) -> f32 ; 3 = bias + in-place add -> f32 ;
//      4 = bias -> bf16 TRANSPOSED per-head: out[(b*1024+ch)*512 + (tok&511)]
template<int EPI>
__global__ __launch_bounds__(256) void gemm_bt(
    const unsigned short* __restrict__ A, const unsigned short* __restrict__ Bt,
    const float* __restrict__ bias, const float* __restrict__ res,
    void* outp, int N, int K)
{
  __shared__ unsigned short As[128 * 32];
  __shared__ unsigned short Bs[128 * 32];
  const int t = threadIdx.x;
  const int lane = t & 63, w = t >> 6;
  const int wr = w >> 1, wc = w & 1;
  const size_t tm = (size_t)blockIdx.y * 128;
  const size_t tn = (size_t)blockIdx.x * 128;

  const int ia1 = w * 64 + lane;
  const int r1 = ia1 >> 2, c1 = (ia1 & 3) * 8;
  const unsigned short* a1 = A  + (tm + r1) * (size_t)K + c1;
  const unsigned short* a2 = A  + (tm + r1 + 64) * (size_t)K + c1;
  const unsigned short* b1 = Bt + (tn + r1) * (size_t)K + c1;
  const unsigned short* b2 = Bt + (tn + r1 + 64) * (size_t)K + c1;
  unsigned short* sA1 = As + w * 512;
  unsigned short* sA2 = As + 2048 + w * 512;
  unsigned short* sB1 = Bs + w * 512;
  unsigned short* sB2 = Bs + 2048 + w * 512;

  f32x4 acc[4][4];
  #pragma unroll
  for (int i = 0; i < 4; i++)
    #pragma unroll
    for (int j = 0; j < 4; j++)
      acc[i][j] = (f32x4){0.f, 0.f, 0.f, 0.f};

  const int ko = (lane >> 4) * 8;
  const int rm = lane & 15;

  for (int k0 = 0; k0 < K; k0 += 32) {
    GLOAD16(a1 + k0, sA1);
    GLOAD16(a2 + k0, sA2);
    GLOAD16(b1 + k0, sB1);
    GLOAD16(b2 + k0, sB2);
    __syncthreads();
    short8 af[4], bfv[4];
    #pragma unroll
    for (int fm = 0; fm < 4; fm++)
      af[fm] = *(const short8*)(As + (wr * 64 + fm * 16 + rm) * 32 + ko);
    #pragma unroll
    for (int fn = 0; fn < 4; fn++)
      bfv[fn] = *(const short8*)(Bs + (wc * 64 + fn * 16 + rm) * 32 + ko);
    #pragma unroll
    for (int fm = 0; fm < 4; fm++)
      #pragma unroll
      for (int fn = 0; fn < 4; fn++)
        acc[fm][fn] = MFMA16(af[fm], bfv[fn], acc[fm][fn]);
    __syncthreads();
  }

  #pragma unroll
  for (int fn = 0; fn < 4; fn++) {
    const size_t gcol = tn + wc * 64 + fn * 16 + rm;
    const float bc = bias[gcol];
    #pragma unroll
    for (int fm = 0; fm < 4; fm++) {
      #pragma unroll
      for (int r = 0; r < 4; r++) {
        const size_t grow = tm + wr * 64 + fm * 16 + (lane >> 4) * 4 + r;
        const size_t off = grow * (size_t)N + gcol;
        float v = acc[fm][fn][r] + bc;
        if (EPI == 0) {
          ((unsigned short*)outp)[off] = f2bf(v);
        } else if (EPI == 1) {
          ((unsigned short*)outp)[off] = f2bf(gelu_f(v));
        } else if (EPI == 2) {
          ((float*)outp)[off] = v + res[off];
        } else if (EPI == 3) {
          float* op = (float*)outp;
          op[off] = v + op[off];
        } else {
          // V^T layout: [b][ch(=h*64+d)][l] ; row = token, col = channel
          const int tok = (int)grow;
          const int bb = tok >> 9, ll = tok & 511;
          ((unsigned short*)outp)[((size_t)bb * 1024 + gcol) * 512 + ll] = f2bf(v);
        }
      }
    }
  }
}

// ---------------- MFMA flash attention ----------------
// grid (qt=4, h=16, b=32), 4 waves. Per wave: 32 q-rows. KBLK=32.
// Q,K staged to LDS with row-XOR swizzle (chunk ^= row&7) via pre-swizzled global src.
// V^T [d][l] staged likewise (chunk ^= d&3). P via per-wave LDS (pad-40 rows).
__global__ __launch_bounds__(256) void attn_mfma(
    const unsigned short* __restrict__ qb, const unsigned short* __restrict__ kb,
    const unsigned short* __restrict__ vt, unsigned short* __restrict__ ctx)
{
  __shared__ unsigned short Qs[128 * 64];      // 16 KB
  __shared__ unsigned short Ks[2][32 * 64];    //  8 KB
  __shared__ unsigned short Vs[2][64 * 32];    //  8 KB
  __shared__ unsigned short Ps[4][32 * 40];    // 10 KB
  const int t = threadIdx.x;
  const int lane = t & 63, w = t >> 6;
  const int g = lane >> 4, rm = lane & 15;
  const int qt = blockIdx.x, h = blockIdx.y, b = blockIdx.z;

  const unsigned short* qg = qb + ((size_t)(b * SEQ + qt * 128)) * DMOD + h * DHEAD;
  const unsigned short* kg = kb + ((size_t)(b * SEQ)) * DMOD + h * DHEAD;
  const unsigned short* vg = vt + ((size_t)(b * NHEAD + h)) * DHEAD * SEQ;  // [64][512]

  // ---- stage Q (128 rows x 128B, swizzled) ----
  #pragma unroll
  for (int ii = 0; ii < 4; ii++) {
    const int i = ii * 256 + t;
    const int r = i >> 3, c = i & 7;
    const int bc = 16 * (c ^ (r & 7));
    GLOAD16(qg + (size_t)r * DMOD + (bc >> 1), Qs + (size_t)(ii * 256 + w * 64) * 8);
  }
  __syncthreads();

  // Q fragments (per wave: rows w*32 .. w*32+31), fold nothing; scale applied to S
  short8 aq[2][2];
  #pragma unroll
  for (int fq = 0; fq < 2; fq++)
    #pragma unroll
    for (int kd = 0; kd < 2; kd++) {
      const int r = w * 32 + fq * 16 + rm;
      aq[fq][kd] = *(const short8*)((const char*)Qs + r * 128 + ((kd * 64 + g * 16) ^ ((r & 7) << 4)));
    }

  float mrow[2][4], lrow[2][4];
  f32x4 of[2][4];
  #pragma unroll
  for (int fq = 0; fq < 2; fq++) {
    #pragma unroll
    for (int j = 0; j < 4; j++) { mrow[fq][j] = -INFINITY; lrow[fq][j] = 0.f; }
    #pragma unroll
    for (int fd = 0; fd < 4; fd++) of[fq][fd] = (f32x4){0.f, 0.f, 0.f, 0.f};
  }

  // staging lambdas: one 16B chunk per thread
  auto stageK = [&](int kt, int bf) {
    const int r = t >> 3, c = t & 7;
    const int bc = 16 * (c ^ (r & 7));
    GLOAD16(kg + (size_t)(kt * 32 + r) * DMOD + (bc >> 1), Ks[bf] + (size_t)w * 512);
  };
  auto stageV = [&](int kt, int bf) {
    const int r = t >> 2, c = t & 3;
    const int bc = 16 * (c ^ (r & 3));
    GLOAD16(vg + (size_t)r * SEQ + kt * 32 + (bc >> 1), Vs[bf] + (size_t)w * 512);
  };

  stageK(0, 0); stageV(0, 0);
  __syncthreads();
  int buf = 0;

  for (int kt = 0; kt < SEQ / 32; kt++) {
    if (kt + 1 < SEQ / 32) { stageK(kt + 1, buf ^ 1); stageV(kt + 1, buf ^ 1); }

    // ---- S = Q K^T  (per wave: 32q x 32k) ----
    f32x4 s[2][2];
    #pragma unroll
    for (int fq = 0; fq < 2; fq++)
      #pragma unroll
      for (int fk = 0; fk < 2; fk++) {
        f32x4 a = (f32x4){0.f, 0.f, 0.f, 0.f};
        #pragma unroll
        for (int kd = 0; kd < 2; kd++) {
          const int r = fk * 16 + rm;
          short8 bk = *(const short8*)((const char*)Ks[buf] + r * 128 + ((kd * 64 + g * 16) ^ ((r & 7) << 4)));
          a = MFMA16(aq[fq][kd], bk, a);
        }
        s[fq][fk] = a;
      }

    // ---- online softmax (rows = g*4+j within fq-block) ----
    #pragma unroll
    for (int fq = 0; fq < 2; fq++) {
      #pragma unroll
      for (int j = 0; j < 4; j++) {
        const float s0 = s[fq][0][j] * 0.125f;
        const float s1 = s[fq][1][j] * 0.125f;
        float mx = fmaxf(s0, s1);
        #pragma unroll
        for (int mk = 1; mk < 16; mk <<= 1) mx = fmaxf(mx, __shfl_xor(mx, mk));
        const float mo = mrow[fq][j];
        const float mn = fmaxf(mo, mx);
        const float corr = __expf(mo - mn);
        mrow[fq][j] = mn;
        const float p0 = __expf(s0 - mn);
        const float p1 = __expf(s1 - mn);
        float rs = p0 + p1;
        #pragma unroll
        for (int mk = 1; mk < 16; mk <<= 1) rs += __shfl_xor(rs, mk);
        lrow[fq][j] = lrow[fq][j] * corr + rs;
        #pragma unroll
        for (int fd = 0; fd < 4; fd++) of[fq][fd][j] *= corr;
        Ps[w][(fq * 16 + g * 4 + j) * 40 + rm]      = f2bf(p0);
        Ps[w][(fq * 16 + g * 4 + j) * 40 + 16 + rm] = f2bf(p1);
      }
    }

    // ---- O += P V ----
    #pragma unroll
    for (int fq = 0; fq < 2; fq++) {
      const short8 pa = *(const short8*)((const char*)Ps[w] + (fq * 16 + rm) * 80 + g * 16);
      #pragma unroll
      for (int fd = 0; fd < 4; fd++) {
        const int r = fd * 16 + rm;
        const short8 vb = *(const short8*)((const char*)Vs[buf] + r * 64 + ((g * 16) ^ ((r & 3) << 4)));
        of[fq][fd] = MFMA16(pa, vb, of[fq][fd]);
      }
    }

    __syncthreads();
    buf ^= 1;
  }

  // ---- epilogue: O / l -> ctx ----
  #pragma unroll
  for (int fq = 0; fq < 2; fq++)
    #pragma unroll
    for (int j = 0; j < 4; j++) {
      const float inv = 1.f / lrow[fq][j];
      const size_t q = (size_t)b * SEQ + qt * 128 + w * 32 + fq * 16 + g * 4 + j;
      #pragma unroll
      for (int fd = 0; fd < 4; fd++)
        ctx[q * DMOD + h * DHEAD + fd * 16 + rm] = f2bf(of[fq][fd][j] * inv);
    }
}

extern "C" void kernel_launch(void* const* d_in, const int* in_sizes, int n_in,
                              void* d_out, int out_size, void* d_ws, size_t ws_size,
                              hipStream_t stream) {
  const float* x_a   = (const float*)d_in[0];
  const float* x_b   = (const float*)d_in[1];
  const float* spk   = (const float*)d_in[2];
  const float* Wq    = (const float*)d_in[3];
  const float* bq    = (const float*)d_in[4];
  const float* Wk    = (const float*)d_in[5];
  const float* bk    = (const float*)d_in[6];
  const float* Wv    = (const float*)d_in[7];
  const float* bv    = (const float*)d_in[8];
  const float* Wo    = (const float*)d_in[9];
  const float* bo    = (const float*)d_in[10];
  const float* ln_g  = (const float*)d_in[11];
  const float* ln_b  = (const float*)d_in[12];
  const float* fln_g = (const float*)d_in[13];
  const float* fln_b = (const float*)d_in[14];
  const float* W1    = (const float*)d_in[15];
  const float* b1    = (const float*)d_in[16];
  const float* W2    = (const float*)d_in[17];
  const float* b2    = (const float*)d_in[18];
  float* out = (float*)d_out;           // also serves as the f32 x_b master (X)

  char* ws = (char*)d_ws;
  size_t o = 0;
  auto give = [&](size_t bytes) { char* p = ws + o; o += (bytes + 255) & ~(size_t)255; return p; };
  const size_t ACT2 = (size_t)NTOK * DMOD * 2;   // 32 MB bf16 activation

  unsigned short* qb16  = (unsigned short*)give(ACT2);       // also inter lo
  unsigned short* kb16  = (unsigned short*)give(ACT2);       // also inter hi
  unsigned short* vt16  = (unsigned short*)give(ACT2);       // V^T [b][h][d][l]
  unsigned short* xa16  = (unsigned short*)give(ACT2);
  unsigned short* xbn16 = (unsigned short*)give(ACT2);
  unsigned short* ctx16 = (unsigned short*)give(ACT2);
  float*          outf  = (float*)give((size_t)NTOK * DMOD * 4);   // 64 MB (residual stream)
  unsigned short* Wqt   = (unsigned short*)give((size_t)DMOD * DMOD * 2);
  unsigned short* Wkt   = (unsigned short*)give((size_t)DMOD * DMOD * 2);
  unsigned short* Wvt   = (unsigned short*)give((size_t)DMOD * DMOD * 2);
  unsigned short* Wot   = (unsigned short*)give((size_t)DMOD * DMOD * 2);
  unsigned short* W1t   = (unsigned short*)give((size_t)DMOD * DFFN * 2);
  unsigned short* W2t   = (unsigned short*)give((size_t)DMOD * DFFN * 2);
  float*          peb   = (float*)give((size_t)SEQ * DMOD * 4);
  unsigned short* inter = qb16;     // 64 MB span over qb16+kb16 (dead during FFN)
  (void)ws_size; (void)in_sizes; (void)n_in; (void)out_size;

  const dim3 blk(256);

  pe_kernel<<<dim3((SEQ * (DMOD / 2)) / 256), blk, 0, stream>>>(peb);
  const int nprep = (NTOK * DMOD / 4) / 256;
  prep_kernel<<<dim3(nprep), blk, 0, stream>>>(x_a, peb, spk, nullptr, xa16);
  prep_kernel<<<dim3(nprep), blk, 0, stream>>>(x_b, peb, spk, out, xbn16);

  const dim3 g1024(DMOD / 128, NTOK / 128);   // (8,128)
  const int  MCH = NTOK / 2;                  // FFN token-chunk (8192 rows)

  for (int i = 0; i < NLAY; i++) {
    const size_t wo = (size_t)i * DMOD * DMOD;
    const size_t wf = (size_t)i * DMOD * DFFN;
    wtrans_kernel<<<dim3(16, 16), blk, 0, stream>>>(Wq + wo, Wqt, DMOD, DMOD);
    wtrans_kernel<<<dim3(16, 16), blk, 0, stream>>>(Wk + wo, Wkt, DMOD, DMOD);
    wtrans_kernel<<<dim3(16, 16), blk, 0, stream>>>(Wv + wo, Wvt, DMOD, DMOD);
    wtrans_kernel<<<dim3(16, 16), blk, 0, stream>>>(Wo + wo, Wot, DMOD, DMOD);
    wtrans_kernel<<<dim3(64, 16), blk, 0, stream>>>(W1 + wf, W1t, DMOD, DFFN);
    wtrans_kernel<<<dim3(16, 64), blk, 0, stream>>>(W2 + wf, W2t, DFFN, DMOD);

    if (i != 0) {
      ln_kernel<1><<<dim3(NTOK), blk, 0, stream>>>(out, ln_g + (size_t)i * DMOD, ln_b + (size_t)i * DMOD, outf, xbn16);
    }
    gemm_bt<0><<<g1024, blk, 0, stream>>>(xbn16, Wqt, bq + (size_t)i * DMOD, nullptr, qb16, DMOD, DMOD);
    gemm_bt<0><<<g1024, blk, 0, stream>>>(xa16,  Wkt, bk + (size_t)i * DMOD, nullptr, kb16, DMOD, DMOD);
    gemm_bt<4><<<g1024, blk, 0, stream>>>(xa16,  Wvt, bv + (size_t)i * DMOD, nullptr, vt16, DMOD, DMOD);
    attn_mfma<<<dim3(SEQ / 128, NHEAD, BATCH), blk, 0, stream>>>(qb16, kb16, vt16, ctx16);
    if (i == 0) {
      gemm_bt<2><<<g1024, blk, 0, stream>>>(ctx16, Wot, bo + (size_t)i * DMOD, out, outf, DMOD, DMOD);
    } else {
      gemm_bt<3><<<g1024, blk, 0, stream>>>(ctx16, Wot, bo + (size_t)i * DMOD, nullptr, outf, DMOD, DMOD);
    }
    ln_kernel<0><<<dim3(NTOK), blk, 0, stream>>>(outf, fln_g + (size_t)i * DMOD, fln_b + (size_t)i * DMOD, nullptr, xbn16);
    for (int c = 0; c < 2; c++) {
      const size_t moff = (size_t)c * MCH;
      gemm_bt<1><<<dim3(DFFN / 128, MCH / 128), blk, 0, stream>>>(
          xbn16 + moff * DMOD, W1t, b1 + (size_t)i * DFFN, nullptr, inter, DFFN, DMOD);
      gemm_bt<2><<<dim3(DMOD / 128, MCH / 128), blk, 0, stream>>>(
          inter, W2t, b2 + (size_t)i * DMOD, outf + moff * DMOD, out + moff * DMOD, DMOD, DFFN);
    }
  }
}